// Round 13
// baseline (194.352 us; speedup 1.0000x reference)
//
#include <hip/hip_runtime.h>
#include <hip/hip_cooperative_groups.h>

namespace cg = cooperative_groups;

#define BS 16
#define S  256
#define H  1024
#define T  32
#define KSPLIT 4
#define KCH (H / KSPLIT)    // 256 k per gemm block
#define BM 32               // rows per gemm block
#define NBLK 640            // fused grid: 128 ps + 512 gemm

// ws layout (floats): pp[4][4096][64] | ps[512] | p1[4096*32] | p2[4096*32]
#define PP_OFF 0
#define PP_SZ  (KSPLIT * BS * S * 64)           // 1048576 floats
#define PS_OFF (PP_OFF + PP_SZ)
#define P1_OFF (PS_OFF + 512)
#define P2_OFF (P1_OFF + BS * S * T)

typedef __bf16 bf16x8 __attribute__((ext_vector_type(8)));
typedef float  f32x4  __attribute__((ext_vector_type(4)));

__device__ inline bf16x8 to_bf8(float4 lo, float4 hi) {
    bf16x8 r;
    r[0] = (__bf16)lo.x; r[1] = (__bf16)lo.y; r[2] = (__bf16)lo.z; r[3] = (__bf16)lo.w;
    r[4] = (__bf16)hi.x; r[5] = (__bf16)hi.y; r[6] = (__bf16)hi.z; r[7] = (__bf16)hi.w;
    return r;
}

// ---- R10 phase bodies as device functions (shared by fused + fallback) ----

__device__ inline void ps_body(int psblk, int lane, int wv,
    const float* __restrict__ seq, const float* __restrict__ W,
    const float* __restrict__ bias, float* __restrict__ ws)
{
    float* ps = ws + PS_OFF;
    const int o = psblk * 4 + wv;                 // 0..511
    const int bb = o >> 5, t = o & 31;
    const float4* sp = (const float4*)(seq + (size_t)bb * H) + lane * 4;
    const float4* wp = (const float4*)(W + (size_t)t * (3 * H) + 2 * H) + lane * 4;
    float acc = 0.f;
    #pragma unroll
    for (int k = 0; k < 4; ++k) {
        float4 a = sp[k], w = wp[k];
        acc += a.x * w.x + a.y * w.y + a.z * w.z + a.w * w.w;
    }
    #pragma unroll
    for (int m = 32; m >= 1; m >>= 1) acc += __shfl_xor(acc, m);
    if (lane == 0) ps[o] = acc + bias[t];
}

// Ebf: [BM][280] bf16 (17.5 KB)
__device__ inline void gemm_body(int g, int tid, int lane, int wv,
    __bf16 (*Ebf)[280],
    const float* __restrict__ E, const float* __restrict__ W,
    float* __restrict__ ws)
{
    const int ks = g >> 7;
    const int m0 = (g & 127) * BM;
    const int kbeg = ks * KCH;

    const int nb = wv * 16;
    const int wrow = nb + (lane & 15);            // output col 0..63
    const int ksub = (lane >> 4) * 8;             // k sub-offset 0/8/16/24
    const float* wbase = W + (size_t)(wrow & 31) * (3 * H)
                           + ((wrow >> 5) ? H : 0) + kbeg + ksub;
    bf16x8 bfrag[8];
    #pragma unroll
    for (int s = 0; s < 8; ++s)
        bfrag[s] = to_bf8(*(const float4*)(wbase + s * 32),
                          *(const float4*)(wbase + s * 32 + 4));

    #pragma unroll
    for (int i = 0; i < 4; ++i) {
        int f = tid + i * 256;                    // 0..1023
        int row = f >> 5, c8 = f & 31;
        const float4* src = (const float4*)(E + (size_t)(m0 + row) * H
                                            + kbeg + c8 * 8);
        *(bf16x8*)&Ebf[row][c8 * 8] = to_bf8(src[0], src[1]);
    }
    __syncthreads();

    f32x4 acc0 = {0.f,0.f,0.f,0.f}, acc1 = {0.f,0.f,0.f,0.f};
    const int erow = lane & 15;
    #pragma unroll
    for (int s = 0; s < 8; ++s) {
        bf16x8 a0 = *(const bf16x8*)&Ebf[erow][s * 32 + ksub];
        bf16x8 a1 = *(const bf16x8*)&Ebf[erow + 16][s * 32 + ksub];
        acc0 = __builtin_amdgcn_mfma_f32_16x16x32_bf16(a0, bfrag[s], acc0, 0, 0, 0);
        acc1 = __builtin_amdgcn_mfma_f32_16x16x32_bf16(a1, bfrag[s], acc1, 0, 0, 0);
    }

    float* pp = ws + PP_OFF + (size_t)ks * (BS * S * 64);
    const int orow = (lane >> 4) * 4;
    const int ocol = nb + (lane & 15);
    #pragma unroll
    for (int r = 0; r < 4; ++r) {
        pp[(size_t)(m0 + orow + r) * 64 + ocol]      = acc0[r];
        pp[(size_t)(m0 + 16 + orow + r) * 64 + ocol] = acc1[r];
    }
}

__device__ inline void reduce_body(int o, float* __restrict__ ws)
{
    const float4* pp = (const float4*)(ws + PP_OFF);
    float4 v = pp[o];
    #pragma unroll
    for (int ks = 1; ks < KSPLIT; ++ks) {
        float4 u = pp[o + ks * (PP_SZ / KSPLIT / 4)];
        v.x += u.x; v.y += u.y; v.z += u.z; v.w += u.w;
    }
    const int row = o >> 4, c4 = o & 15;          // row 0..4095
    if (c4 < 8) {
        const int b = row >> 8;
        float4 s = ((const float4*)(ws + PS_OFF))[b * 8 + c4];
        v.x += s.x; v.y += s.y; v.z += s.z; v.w += s.w;
        ((float4*)(ws + P1_OFF))[row * 8 + c4] = v;
    } else {
        ((float4*)(ws + P2_OFF))[row * 8 + (c4 - 8)] = v;
    }
}

__device__ inline void bcast_body(int rowblk, int tid,
    const float* __restrict__ ws, float* __restrict__ out)
{
    const int b = rowblk >> 8, i = rowblk & 255;
    const float4 s = *(const float4*)((ws + P1_OFF)
                     + (size_t)(b * S + i) * T + (tid & 7) * 4);
    const float4* p2v = (const float4*)(ws + P2_OFF) + (size_t)b * (S * T / 4);
    float4* ov = (float4*)out + (size_t)(b * S + i) * (S * T / 4);
    #pragma unroll
    for (int k = tid; k < S * T / 4; k += 256) {
        float4 v = p2v[k];
        float4 r;
        r.x = v.x + s.x; r.y = v.y + s.y; r.z = v.z + s.z; r.w = v.w + s.w;
        ov[k] = r;
    }
}

// ---------------------------------------------------------------------------
// Fused cooperative kernel: 640 blocks x 256 threads, R10 phases + 2 syncs.
// ---------------------------------------------------------------------------
__global__ __launch_bounds__(256, 2) void fused(
    const float* __restrict__ seq, const float* __restrict__ E,
    const float* __restrict__ W, const float* __restrict__ bias,
    float* __restrict__ ws, float* __restrict__ out)
{
    __shared__ __align__(16) __bf16 Ebf[BM][280];
    const int tid = threadIdx.x;
    const int lane = tid & 63, wv = tid >> 6;
    const int blk = blockIdx.x;

    if (blk < 128) ps_body(blk, lane, wv, seq, W, bias, ws);
    else           gemm_body(blk - 128, tid, lane, wv, Ebf, E, W, ws);

    cg::this_grid().sync();

    { const int o = blk * 256 + tid; if (o < 65536) reduce_body(o, ws); }

    cg::this_grid().sync();

    for (int r = blk; r < BS * S; r += NBLK) bcast_body(r, tid, ws, out);
}

// ---------------------------------------------------------------------------
// Fallback kernels (R10 exact pipeline)
// ---------------------------------------------------------------------------
__global__ __launch_bounds__(256) void gemm_ps_k(
    const float* __restrict__ seq, const float* __restrict__ E,
    const float* __restrict__ W, const float* __restrict__ bias,
    float* __restrict__ ws)
{
    __shared__ __align__(16) __bf16 Ebf[BM][280];
    const int tid = threadIdx.x;
    const int lane = tid & 63, wv = tid >> 6;
    if (blockIdx.x < 128) ps_body(blockIdx.x, lane, wv, seq, W, bias, ws);
    else                  gemm_body(blockIdx.x - 128, tid, lane, wv, Ebf, E, W, ws);
}

__global__ __launch_bounds__(256) void reduce_p_k(float* __restrict__ ws)
{
    reduce_body(blockIdx.x * 256 + threadIdx.x, ws);
}

__global__ __launch_bounds__(256) void bcast_add_k(
    const float* __restrict__ ws, float* __restrict__ out)
{
    bcast_body(blockIdx.x, threadIdx.x, ws, out);
}

extern "C" void kernel_launch(void* const* d_in, const int* in_sizes, int n_in,
                              void* d_out, int out_size, void* d_ws, size_t ws_size,
                              hipStream_t stream)
{
    const float* seq  = (const float*)d_in[0];   // (16,1024)
    const float* E    = (const float*)d_in[1];   // (16,256,1024)
    const float* W    = (const float*)d_in[2];   // (32,3072)
    const float* bias = (const float*)d_in[3];   // (32,)
    float* out = (float*)d_out;                  // (16,256,256,32) f32
    float* ws  = (float*)d_ws;                   // ~5.3 MB used

    void* args[] = {(void*)&seq, (void*)&E, (void*)&W, (void*)&bias,
                    (void*)&ws, (void*)&out};
    hipError_t err = hipLaunchCooperativeKernel((const void*)fused,
                        dim3(NBLK), dim3(256), args, 0, stream);
    if (err != hipSuccess) {
        // Fallback: proven R10 3-kernel pipeline (identical math).
        gemm_ps_k<<<640, 256, 0, stream>>>(seq, E, W, bias, ws);
        reduce_p_k<<<256, 256, 0, stream>>>(ws);
        bcast_add_k<<<BS * S, 256, 0, stream>>>(ws, out);
    }
}

// Round 14
// 37.933 us; speedup vs baseline: 5.1236x; 5.1236x over previous
//
#include <hip/hip_runtime.h>

#define BS 16
#define S  256
#define H  1024
#define T  32

// ws layout (floats): ps[512] | p1[4096*32] | p2[4096*32]   (p1,p2 FINAL)
#define PS_OFF 0
#define P1_OFF 512
#define P2_OFF (P1_OFF + BS * S * T)

typedef __bf16 bf16x8 __attribute__((ext_vector_type(8)));
typedef float  f32x4  __attribute__((ext_vector_type(4)));

__device__ inline bf16x8 to_bf8(float4 lo, float4 hi) {
    bf16x8 r;
    r[0] = (__bf16)lo.x; r[1] = (__bf16)lo.y; r[2] = (__bf16)lo.z; r[3] = (__bf16)lo.w;
    r[4] = (__bf16)hi.x; r[5] = (__bf16)hi.y; r[6] = (__bf16)hi.z; r[7] = (__bf16)hi.w;
    return r;
}

// ---------------------------------------------------------------------------
// Kernel A, 512-thread blocks (8 waves):
//   blk < 64 : ps — one wave per (b,t): o = blk*8+wv, coalesced + shfl_xor.
//   blk >= 64: GEMM, BM=16, intra-block K-split: wave = (kc=wv>>2, cg=wv&3);
//     k-chunk 512. Per wave: 16 cols x 512 k B-frags (16 bf16x8 — 2x R10,
//     half of R8's failed 4x), E from LDS (staged once as bf16, 33 KB,
//     stride 1032 pad -> 2-way alias = free), 16 MFMAs. pacc[2] LDS reduce
//     (8 KB) + 1 barrier -> p1/p2 written FINAL. No reduce kernel, no pp.
// ---------------------------------------------------------------------------
__global__ __launch_bounds__(512) void gemm_ps(
    const float* __restrict__ seq, const float* __restrict__ E,
    const float* __restrict__ W, const float* __restrict__ bias,
    float* __restrict__ ws)
{
    const int tid = threadIdx.x;
    const int lane = tid & 63, wv = tid >> 6;

    if (blockIdx.x < 64) {
        // ---- ps[b,t] = seq[b,:] . W[t,2H:3H] + bias[t], wave-parallel ----
        float* ps = ws + PS_OFF;
        const int o = blockIdx.x * 8 + wv;            // 0..511
        const int bb = o >> 5, t = o & 31;
        const float4* sp = (const float4*)(seq + (size_t)bb * H) + lane * 4;
        const float4* wp = (const float4*)(W + (size_t)t * (3 * H) + 2 * H) + lane * 4;
        float acc = 0.f;
        #pragma unroll
        for (int k = 0; k < 4; ++k) {
            float4 a = sp[k], w = wp[k];
            acc += a.x * w.x + a.y * w.y + a.z * w.z + a.w * w.w;
        }
        #pragma unroll
        for (int m = 32; m >= 1; m >>= 1) acc += __shfl_xor(acc, m);
        if (lane == 0) ps[o] = acc + bias[t];
        return;
    }

    __shared__ __align__(16) __bf16 Ebf[16][1032];    // 33 KB
    __shared__ __align__(16) float  pacc[2][16][64];  // 8 KB

    const int m0 = (blockIdx.x - 64) * 16;
    const int kc = wv >> 2;                           // k-chunk 0/1
    const int cg = wv & 3;                            // col-group 0..3
    const int kbeg = kc * 512;

    // ---- issue E tile loads first (HBM, longest latency) ----
    float4 tmpa[4], tmpb[4];
    #pragma unroll
    for (int i = 0; i < 4; ++i) {
        int c = tid + i * 512;                        // 0..2047 chunks of 8
        int row = c >> 7, c8 = c & 127;
        const float4* src = (const float4*)(E + (size_t)(m0 + row) * H + c8 * 8);
        tmpa[i] = src[0]; tmpb[i] = src[1];
    }

    // ---- B fragments: 16 cols x 512 k (L2-hot W), overlap with E loads ----
    const int col = cg * 16 + (lane & 15);            // output col 0..63
    const int ksub = (lane >> 4) * 8;                 // k sub-offset 0/8/16/24
    const float* wbase = W + (size_t)(col & 31) * (3 * H)
                           + ((col >= 32) ? H : 0) + kbeg + ksub;
    bf16x8 bfrag[16];
    #pragma unroll
    for (int s = 0; s < 16; ++s)
        bfrag[s] = to_bf8(*(const float4*)(wbase + s * 32),
                          *(const float4*)(wbase + s * 32 + 4));

    // ---- E -> bf16 LDS ----
    #pragma unroll
    for (int i = 0; i < 4; ++i) {
        int c = tid + i * 512;
        int row = c >> 7, c8 = c & 127;
        *(bf16x8*)&Ebf[row][c8 * 8] = to_bf8(tmpa[i], tmpb[i]);
    }
    __syncthreads();

    // ---- 16 MFMAs over this wave's k-chunk ----
    f32x4 acc = {0.f, 0.f, 0.f, 0.f};
    const int erow = lane & 15;
    #pragma unroll
    for (int s = 0; s < 16; ++s) {
        bf16x8 a = *(const bf16x8*)&Ebf[erow][kbeg + s * 32 + ksub];
        acc = __builtin_amdgcn_mfma_f32_16x16x32_bf16(a, bfrag[s], acc, 0, 0, 0);
    }

    // ---- partials -> LDS (D layout: col=lane&15, row=(lane>>4)*4+r) ----
    const int orow = (lane >> 4) * 4;
    #pragma unroll
    for (int r = 0; r < 4; ++r)
        pacc[kc][orow + r][col] = acc[r];
    __syncthreads();

    // ---- k-reduce + final write: 1024 elems over 512 threads ----
    #pragma unroll
    for (int e = tid; e < 1024; e += 512) {
        const int row = e >> 6, c = e & 63;
        float v = pacc[0][row][c] + pacc[1][row][c];
        if (c < 32) (ws + P1_OFF)[(size_t)(m0 + row) * T + c] = v;
        else        (ws + P2_OFF)[(size_t)(m0 + row) * T + (c - 32)] = v;
    }
}

// ---------------------------------------------------------------------------
// Kernel B: out[b,i,j,t] = (p1[b,i,t] + ps[b,t]) + p2[b,j,t]
//   Barrier-free prologue (both reads L2-hot); coalesced float4 stream.
// ---------------------------------------------------------------------------
__global__ __launch_bounds__(256) void bcast_add(
    const float* __restrict__ ws, float* __restrict__ out)
{
    const int blk = blockIdx.x;
    const int b = blk >> 8, i = blk & 255;
    const int tid = threadIdx.x;

    const float4 s1v = *(const float4*)((ws + P1_OFF)
                       + (size_t)(b * S + i) * T + (tid & 7) * 4);
    const float4 psv = *(const float4*)((ws + PS_OFF) + b * T + (tid & 7) * 4);
    float4 s;
    s.x = s1v.x + psv.x; s.y = s1v.y + psv.y;
    s.z = s1v.z + psv.z; s.w = s1v.w + psv.w;

    const float4* p2v = (const float4*)(ws + P2_OFF) + (size_t)b * (S * T / 4);
    float4* ov = (float4*)out + (size_t)(b * S + i) * (S * T / 4);

    #pragma unroll
    for (int k = tid; k < S * T / 4; k += 256) {
        float4 v = p2v[k];
        float4 r;
        r.x = v.x + s.x; r.y = v.y + s.y; r.z = v.z + s.z; r.w = v.w + s.w;
        ov[k] = r;
    }
}

extern "C" void kernel_launch(void* const* d_in, const int* in_sizes, int n_in,
                              void* d_out, int out_size, void* d_ws, size_t ws_size,
                              hipStream_t stream)
{
    const float* seq  = (const float*)d_in[0];   // (16,1024)
    const float* E    = (const float*)d_in[1];   // (16,256,1024)
    const float* W    = (const float*)d_in[2];   // (32,3072)
    const float* bias = (const float*)d_in[3];   // (32,)
    float* out = (float*)d_out;                  // (16,256,256,32) f32
    float* ws  = (float*)d_ws;                   // ~1.05 MB used

    gemm_ps<<<320, 512, 0, stream>>>(seq, E, W, bias, ws);
    bcast_add<<<BS * S, 256, 0, stream>>>(ws, out);
}